// Round 7
// baseline (216.099 us; speedup 1.0000x reference)
//
#include <hip/hip_runtime.h>

#define T_DIM 8192
#define NTH 512
#define NWAVE 8
#define NBIN 2048
#define KEEP_K 2867                 // max(1, round(8192 * 0.35))
#define KSCALE 32768.0f             // 16-bit fixed-point key scale (scores < 2.0)
#define INV_KSCALE (1.0f / 32768.0f)
#define BINW (32.0f / 32768.0f)     // key>>5 -> 2048 bins

typedef float nt4 __attribute__((ext_vector_type(4)));

__global__ __launch_bounds__(NTH, 4) void srp_kernel(
    const float* __restrict__ g_anchor,
    const float* __restrict__ g_lr,
    const float* __restrict__ g_pw,
    const float* __restrict__ g_bl,
    const float* __restrict__ g_mask,
    const float* __restrict__ g_sbud,
    const float* __restrict__ g_pbud,
    const float* __restrict__ g_psp,
    const float* __restrict__ g_ppa,
    const int*  __restrict__ g_front,
    float* __restrict__ g_out,
    int n_rows)
{
    constexpr float MIN_SPEECH = 1.0f;
    constexpr float MAX_EXPAND = 3.0f;
    constexpr float MIN_BW = 0.1f;
    constexpr float BIAS_W = 0.15f;
    constexpr float INV_TEMP = 1.0f / 0.12f;

    __shared__ unsigned s_cnt[NBIN];     // 8 KB: count histogram
    __shared__ float    s_ws[NBIN];      // 8 KB: sum of s*m*tail^2 per bin
    __shared__ float wred[NWAVE][5];
    __shared__ float s_res[2];           // [0]=thr, [1]=scale_p

    const int b = blockIdx.x;
    const int tid = threadIdx.x;
    const int wave = tid >> 6;
    const int lane = tid & 63;
    const long long row = (long long)b * T_DIM;
    const int f = g_front[b];
    const float sbud = g_sbud[b];
    const float pbud = g_pbud[b];

    #pragma unroll
    for (int i = 0; i < NBIN / NTH; ++i) {
        s_cnt[tid + NTH * i] = 0u;
        s_ws[tid + NTH * i]  = 0.f;
    }
    __syncthreads();                                                    // B0 (pre-load, cheap)

    float SC1[16];   // pre? ps*m^2 : cand*m^2     (speech)
    float PM[16];    // pre? pp*m^2 : m            (pause)
    unsigned kp[8];  // 16 packed 16-bit score keys
    float a_ps = 0.f, a_pp = 0.f, a_ts = 0.f, a_cs = 0.f, a_t2 = 0.f;

    // ---------- Pass 1: two half-batches; 14 loads in flight per batch ----------
    #pragma unroll
    for (int h = 0; h < 2; ++h) {
        float4 an[2], lr[2], pw[2], bl[2], mk[2], ps[2], pp[2];
        #pragma unroll
        for (int g = 0; g < 2; ++g) {               // issue ALL loads first (MLP)
            const int t0 = (h * 2 + g) * 2048 + (tid << 2);
            an[g] = *reinterpret_cast<const float4*>(g_anchor + row + t0);
            lr[g] = *reinterpret_cast<const float4*>(g_lr + row + t0);
            pw[g] = *reinterpret_cast<const float4*>(g_pw + row + t0);
            bl[g] = *reinterpret_cast<const float4*>(g_bl + row + t0);
            mk[g] = *reinterpret_cast<const float4*>(g_mask + row + t0);
            ps[g] = *reinterpret_cast<const float4*>(g_psp + row + t0);
            pp[g] = *reinterpret_cast<const float4*>(g_ppa + row + t0);
        }
        #pragma unroll
        for (int g = 0; g < 2; ++g) {               // then consume
            const int t0 = (h * 2 + g) * 2048 + (tid << 2);
            unsigned kk0 = 0u, kk1 = 0u;
            #pragma unroll
            for (int c = 0; c < 4; ++c) {
                const int i = (h * 2 + g) * 4 + c;
                const int t = t0 + c;
                const float m   = (&mk[g].x)[c];
                const float pre = (t < f) ? 1.0f : 0.0f;
                const float tl  = m * (1.0f - pre);
                const float psv = (&ps[g].x)[c];
                const float ppv = (&pp[g].x)[c];
                a_ps += psv * m * pre;
                a_pp += ppv * m * pre;
                a_ts += tl;
                a_t2 += tl * tl;
                const float anv = fmaxf((&an[g].x)[c], MIN_SPEECH);
                const float cand = fminf(fmaxf(anv * __expf((&lr[g].x)[c]), MIN_SPEECH),
                                         anv * MAX_EXPAND) * m;
                a_cs += cand * tl;
                const float s = (fmaxf((&pw[g].x)[c], 0.0f)
                                 + BIAS_W * (MIN_BW + fmaxf((&bl[g].x)[c], 0.0f))) * m;
                const unsigned key = (unsigned)fminf(s * KSCALE, 65535.0f);
                atomicAdd(&s_cnt[key >> 5], 1u);
                const float w = s * m * tl * tl;
                if (w > 0.0f) atomicAdd(&s_ws[key >> 5], w);
                if (c < 2) kk0 |= key << (16 * c);
                else       kk1 |= key << (16 * (c - 2));
                SC1[i] = psv * m * m * pre + cand * tl * m;
                PM[i]  = (t < f) ? ppv * m * m : m;
            }
            kp[2 * (h * 2 + g) / 2 * 2 + 0] = kk0;  // kp[2*(h*2+g)] simplified below
            kp[(h * 2 + g) * 2]     = kk0;
            kp[(h * 2 + g) * 2 + 1] = kk1;
        }
    }

    #pragma unroll
    for (int o = 32; o > 0; o >>= 1) {
        a_ps += __shfl_down(a_ps, o, 64);
        a_pp += __shfl_down(a_pp, o, 64);
        a_ts += __shfl_down(a_ts, o, 64);
        a_cs += __shfl_down(a_cs, o, 64);
        a_t2 += __shfl_down(a_t2, o, 64);
    }
    if (lane == 0) {
        wred[wave][0] = a_ps; wred[wave][1] = a_pp;
        wred[wave][2] = a_ts; wred[wave][3] = a_cs;
        wred[wave][4] = a_t2;
    }
    __syncthreads();                                                    // B1

    // every thread computes row scalars from wred (LDS broadcast reads)
    float ps = 0.f, pp = 0.f, ts = 0.f, cs = 0.f, t2 = 0.f;
    #pragma unroll
    for (int w = 0; w < NWAVE; ++w) {
        ps += wred[w][0]; pp += wred[w][1]; ts += wred[w][2];
        cs += wred[w][3]; t2 += wred[w][4];
    }
    const float sb = fmaxf(sbud, ps + ts * MIN_SPEECH);
    const float pb = fmaxf(pbud, pp);
    const float rem_s = sb - ps;
    const float scale_s = (ts > 0.0f && rem_s > 0.0f) ? (rem_s / fmaxf(cs, 1e-6f)) : 0.0f;
    const float rem_p = fmaxf(pb - pp, 0.0f);
    const float inv_ts6 = 1e-6f / fmaxf(ts, 1.0f);

    if (wave == 0) {
        // ---- threshold scan (lane0 = topmost 32 bins) ----
        const int base = NBIN - 32 * (lane + 1);
        unsigned csum = 0;
        #pragma unroll
        for (int i = 0; i < 32; ++i) csum += s_cnt[base + i];
        unsigned tot = csum;
        #pragma unroll
        for (int off = 1; off < 64; off <<= 1) {
            const unsigned n = __shfl_up(tot, off, 64);
            if (lane >= off) tot += n;
        }
        const unsigned excl = tot - csum;
        float thr_l = -1.0f;
        if (excl < KEEP_K && excl + csum >= KEEP_K) {
            const unsigned need = KEEP_K - excl;
            unsigned c = 0;
            int bin = base;
            for (int i = 31; i >= 0; --i) {
                c += s_cnt[base + i];
                if (c >= need) { bin = base + i; break; }
            }
            thr_l = (float)bin * BINW;
        }
        // broadcast thr across wave (exactly one lane has it)
        #pragma unroll
        for (int off = 32; off > 0; off >>= 1)
            thr_l = fmaxf(thr_l, __shfl_down(thr_l, off, 64));
        thr_l = __shfl(thr_l, 0, 64);
        // ---- denominator from weighted histogram: 32 bins/lane ----
        float a_d = 0.0f;
        #pragma unroll
        for (int i = 0; i < 32; ++i) {
            const int bin = lane + 64 * i;           // stride-1 across lanes
            const float w = s_ws[bin];
            const float sc = ((float)bin + 0.5f) * BINW;
            a_d += w / (1.0f + __expf(-(sc - thr_l) * INV_TEMP));
        }
        #pragma unroll
        for (int off = 32; off > 0; off >>= 1) a_d += __shfl_down(a_d, off, 64);
        if (lane == 0) {
            const float denom = fmaxf(a_d + t2 * inv_ts6, 1e-6f);
            s_res[0] = thr_l;
            s_res[1] = (ts > 0.0f && rem_p > 0.0f) ? (rem_p / denom) : 0.0f;
        }
    } else {
        // ---- speech store overlaps wave0's serial work ----
        #pragma unroll
        for (int g = 0; g < 4; ++g) {
            const int t0 = g * 2048 + (tid << 2);
            nt4 vs;
            #pragma unroll
            for (int c = 0; c < 4; ++c) {
                const int i = (g << 2) + c;
                vs[c] = (t0 + c < f) ? SC1[i] : SC1[i] * scale_s;
            }
            __builtin_nontemporal_store(vs, reinterpret_cast<nt4*>(g_out + row + t0));
        }
    }
    __syncthreads();                                                    // B2

    const float thr = s_res[0];
    const float scale_p = s_res[1];
    const long long out_off = (long long)n_rows * T_DIM;

    if (wave == 0) {                                  // wave0's deferred speech store
        #pragma unroll
        for (int g = 0; g < 4; ++g) {
            const int t0 = g * 2048 + (tid << 2);
            nt4 vs;
            #pragma unroll
            for (int c = 0; c < 4; ++c) {
                const int i = (g << 2) + c;
                vs[c] = (t0 + c < f) ? SC1[i] : SC1[i] * scale_s;
            }
            __builtin_nontemporal_store(vs, reinterpret_cast<nt4*>(g_out + row + t0));
        }
    }

    // ---------- pause compute (keys + PM from registers) + store ----------
    #pragma unroll
    for (int g = 0; g < 4; ++g) {
        const int t0 = g * 2048 + (tid << 2);
        const unsigned kk0 = kp[2 * g], kk1 = kp[2 * g + 1];
        const unsigned kk[4] = { kk0 & 0xFFFFu, kk0 >> 16, kk1 & 0xFFFFu, kk1 >> 16 };
        nt4 vp;
        #pragma unroll
        for (int c = 0; c < 4; ++c) {
            const int i = (g << 2) + c;
            const float pm = PM[i];                  // tail: m ; prefix: pp*m^2
            const float s = (float)kk[c] * INV_KSCALE;
            const float gate = 1.0f / (1.0f + __expf(-(s - thr) * INV_TEMP));
            const float tailv = scale_p * pm * pm * pm * (s * gate * pm + inv_ts6);
            vp[c] = (t0 + c < f) ? pm : tailv;
        }
        __builtin_nontemporal_store(vp, reinterpret_cast<nt4*>(g_out + out_off + row + t0));
    }
}

extern "C" void kernel_launch(void* const* d_in, const int* in_sizes, int n_in,
                              void* d_out, int out_size, void* d_ws, size_t ws_size,
                              hipStream_t stream) {
    const float* anchor = (const float*)d_in[0];
    const float* lr     = (const float*)d_in[1];
    const float* pw     = (const float*)d_in[2];
    const float* bl     = (const float*)d_in[3];
    const float* mask   = (const float*)d_in[4];
    const float* sbud   = (const float*)d_in[5];
    const float* pbud   = (const float*)d_in[6];
    const float* psp    = (const float*)d_in[7];
    const float* ppa    = (const float*)d_in[8];
    const int*   front  = (const int*)d_in[9];
    float* out = (float*)d_out;
    const int B = in_sizes[5];   // speech_budget_win has B elements
    srp_kernel<<<B, NTH, 0, stream>>>(anchor, lr, pw, bl, mask, sbud, pbud,
                                      psp, ppa, front, out, B);
}

// Round 8
// 173.918 us; speedup vs baseline: 1.2425x; 1.2425x over previous
//
#include <hip/hip_runtime.h>

#define T_DIM 8192
#define NTH 512
#define NWAVE 8
#define NBIN 2048
#define KEEP_K 2867                 // max(1, round(8192 * 0.35))
#define KSCALE 32768.0f             // 16-bit fixed-point key scale (scores < 2.0)
#define INV_KSCALE (1.0f / 32768.0f)
#define BINW (32.0f / 32768.0f)     // key>>5 -> 2048 bins

typedef float nt4 __attribute__((ext_vector_type(4)));

// NOTE: launch_bounds min-waves MUST stay <=2: at 4 the compiler pins VGPR=64
// and spills ~100 MB of scratch (rounds 5 & 7 regression signature).
__global__ __launch_bounds__(NTH, 2) void srp_kernel(
    const float* __restrict__ g_anchor,
    const float* __restrict__ g_lr,
    const float* __restrict__ g_pw,
    const float* __restrict__ g_bl,
    const float* __restrict__ g_mask,
    const float* __restrict__ g_sbud,
    const float* __restrict__ g_pbud,
    const float* __restrict__ g_psp,
    const float* __restrict__ g_ppa,
    const int*  __restrict__ g_front,
    float* __restrict__ g_out,
    int n_rows)
{
    constexpr float MIN_SPEECH = 1.0f;
    constexpr float MAX_EXPAND = 3.0f;
    constexpr float MIN_BW = 0.1f;
    constexpr float BIAS_W = 0.15f;
    constexpr float INV_TEMP = 1.0f / 0.12f;

    __shared__ unsigned s_cnt[NBIN];     // 8 KB: count histogram
    __shared__ float    s_ws[NBIN];      // 8 KB: sum of s*m*tail^2 per bin
    __shared__ float wred[NWAVE][5];
    __shared__ float s_res[2];           // [0]=thr, [1]=scale_p

    const int b = blockIdx.x;
    const int tid = threadIdx.x;
    const int wave = tid >> 6;
    const int lane = tid & 63;
    const long long row = (long long)b * T_DIM;
    const int f = g_front[b];
    const float sbud = g_sbud[b];
    const float pbud = g_pbud[b];

    #pragma unroll
    for (int i = 0; i < NBIN / NTH; ++i) {
        s_cnt[tid + NTH * i] = 0u;
        s_ws[tid + NTH * i]  = 0.f;
    }
    __syncthreads();                                  // B0 (before any global loads)

    float SC1[16];   // pre? ps*m^2 : cand*tail*m   (speech)
    float PM[16];    // pre? pp*m^2 : m             (pause)
    unsigned kp[8];  // 16 packed 16-bit score keys
    float a_ps = 0.f, a_pp = 0.f, a_ts = 0.f, a_cs = 0.f, a_t2 = 0.f;

    // ---------- Pass 1: double-buffered prefetch, 4 groups of 7 float4 loads ----------
    float4 an[2], lr[2], pw[2], bl[2], mk[2], ps[2], pp[2];
    {
        const int t0 = tid << 2;
        an[0] = *reinterpret_cast<const float4*>(g_anchor + row + t0);
        lr[0] = *reinterpret_cast<const float4*>(g_lr + row + t0);
        pw[0] = *reinterpret_cast<const float4*>(g_pw + row + t0);
        bl[0] = *reinterpret_cast<const float4*>(g_bl + row + t0);
        mk[0] = *reinterpret_cast<const float4*>(g_mask + row + t0);
        ps[0] = *reinterpret_cast<const float4*>(g_psp + row + t0);
        pp[0] = *reinterpret_cast<const float4*>(g_ppa + row + t0);
    }
    #pragma unroll
    for (int g = 0; g < 4; ++g) {
        const int cur = g & 1;
        if (g < 3) {                                  // prefetch next group
            const int nxt = cur ^ 1;
            const int tn = (g + 1) * 2048 + (tid << 2);
            an[nxt] = *reinterpret_cast<const float4*>(g_anchor + row + tn);
            lr[nxt] = *reinterpret_cast<const float4*>(g_lr + row + tn);
            pw[nxt] = *reinterpret_cast<const float4*>(g_pw + row + tn);
            bl[nxt] = *reinterpret_cast<const float4*>(g_bl + row + tn);
            mk[nxt] = *reinterpret_cast<const float4*>(g_mask + row + tn);
            ps[nxt] = *reinterpret_cast<const float4*>(g_psp + row + tn);
            pp[nxt] = *reinterpret_cast<const float4*>(g_ppa + row + tn);
        }
        const int t0 = g * 2048 + (tid << 2);
        unsigned kk0 = 0u, kk1 = 0u;
        #pragma unroll
        for (int c = 0; c < 4; ++c) {
            const int i = (g << 2) + c;
            const int t = t0 + c;
            const float m   = (&mk[cur].x)[c];
            const float pre = (t < f) ? 1.0f : 0.0f;
            const float tl  = m * (1.0f - pre);
            const float psv = (&ps[cur].x)[c];
            const float ppv = (&pp[cur].x)[c];
            a_ps += psv * m * pre;
            a_pp += ppv * m * pre;
            a_ts += tl;
            a_t2 += tl * tl;
            const float anv = fmaxf((&an[cur].x)[c], MIN_SPEECH);
            const float cand = fminf(fmaxf(anv * __expf((&lr[cur].x)[c]), MIN_SPEECH),
                                     anv * MAX_EXPAND) * m;
            a_cs += cand * tl;
            const float s = (fmaxf((&pw[cur].x)[c], 0.0f)
                             + BIAS_W * (MIN_BW + fmaxf((&bl[cur].x)[c], 0.0f))) * m;
            const unsigned key = (unsigned)fminf(s * KSCALE, 65535.0f);
            atomicAdd(&s_cnt[key >> 5], 1u);
            const float w = s * m * tl * tl;
            if (w > 0.0f) atomicAdd(&s_ws[key >> 5], w);
            if (c < 2) kk0 |= key << (16 * c);
            else       kk1 |= key << (16 * (c - 2));
            SC1[i] = psv * m * m * pre + cand * tl * m;
            PM[i]  = (t < f) ? ppv * m * m : m;
        }
        kp[2 * g]     = kk0;
        kp[2 * g + 1] = kk1;
    }

    #pragma unroll
    for (int o = 32; o > 0; o >>= 1) {
        a_ps += __shfl_down(a_ps, o, 64);
        a_pp += __shfl_down(a_pp, o, 64);
        a_ts += __shfl_down(a_ts, o, 64);
        a_cs += __shfl_down(a_cs, o, 64);
        a_t2 += __shfl_down(a_t2, o, 64);
    }
    if (lane == 0) {
        wred[wave][0] = a_ps; wred[wave][1] = a_pp;
        wred[wave][2] = a_ts; wred[wave][3] = a_cs;
        wred[wave][4] = a_t2;
    }
    __syncthreads();                                                    // B1

    // all threads compute row scalars from wred (LDS broadcast)
    float ps_s = 0.f, pp_s = 0.f, ts = 0.f, cs = 0.f, t2 = 0.f;
    #pragma unroll
    for (int w = 0; w < NWAVE; ++w) {
        ps_s += wred[w][0]; pp_s += wred[w][1]; ts += wred[w][2];
        cs += wred[w][3]; t2 += wred[w][4];
    }
    const float sb = fmaxf(sbud, ps_s + ts * MIN_SPEECH);
    const float pb = fmaxf(pbud, pp_s);
    const float rem_s = sb - ps_s;
    const float scale_s = (ts > 0.0f && rem_s > 0.0f) ? (rem_s / fmaxf(cs, 1e-6f)) : 0.0f;
    const float rem_p = fmaxf(pb - pp_s, 0.0f);
    const float inv_ts6 = 1e-6f / fmaxf(ts, 1.0f);

    if (wave == 0) {
        // ---- threshold scan: lane0 owns topmost 32 bins ----
        const int base = NBIN - 32 * (lane + 1);
        unsigned csum = 0;
        #pragma unroll
        for (int i = 0; i < 32; ++i) csum += s_cnt[base + i];
        unsigned tot = csum;
        #pragma unroll
        for (int off = 1; off < 64; off <<= 1) {
            const unsigned n = __shfl_up(tot, off, 64);
            if (lane >= off) tot += n;
        }
        const unsigned excl = tot - csum;
        float thr_l = -1.0f;
        if (excl < KEEP_K && excl + csum >= KEEP_K) {
            const unsigned need = KEEP_K - excl;
            unsigned c = 0;
            int bin = base;
            for (int i = 31; i >= 0; --i) {
                c += s_cnt[base + i];
                if (c >= need) { bin = base + i; break; }
            }
            thr_l = (float)bin * BINW;
        }
        #pragma unroll
        for (int off = 32; off > 0; off >>= 1)
            thr_l = fmaxf(thr_l, __shfl_down(thr_l, off, 64));
        thr_l = __shfl(thr_l, 0, 64);
        // ---- denominator: 32 bins/lane over weighted histogram ----
        float a_d = 0.0f;
        #pragma unroll
        for (int i = 0; i < 32; ++i) {
            const int bin = lane + 64 * i;
            const float w = s_ws[bin];
            const float sc = ((float)bin + 0.5f) * BINW;
            a_d += w / (1.0f + __expf(-(sc - thr_l) * INV_TEMP));
        }
        #pragma unroll
        for (int off = 32; off > 0; off >>= 1) a_d += __shfl_down(a_d, off, 64);
        if (lane == 0) {
            const float denom = fmaxf(a_d + t2 * inv_ts6, 1e-6f);
            s_res[0] = thr_l;
            s_res[1] = (ts > 0.0f && rem_p > 0.0f) ? (rem_p / denom) : 0.0f;
        }
    } else {
        // ---- speech store overlaps wave0's serial scan ----
        #pragma unroll
        for (int g = 0; g < 4; ++g) {
            const int t0 = g * 2048 + (tid << 2);
            nt4 vs;
            #pragma unroll
            for (int c = 0; c < 4; ++c) {
                const int i = (g << 2) + c;
                vs[c] = (t0 + c < f) ? SC1[i] : SC1[i] * scale_s;
            }
            __builtin_nontemporal_store(vs, reinterpret_cast<nt4*>(g_out + row + t0));
        }
    }
    __syncthreads();                                                    // B2

    const float thr = s_res[0];
    const float scale_p = s_res[1];
    const long long out_off = (long long)n_rows * T_DIM;

    if (wave == 0) {                                  // wave0's deferred speech store
        #pragma unroll
        for (int g = 0; g < 4; ++g) {
            const int t0 = g * 2048 + (tid << 2);
            nt4 vs;
            #pragma unroll
            for (int c = 0; c < 4; ++c) {
                const int i = (g << 2) + c;
                vs[c] = (t0 + c < f) ? SC1[i] : SC1[i] * scale_s;
            }
            __builtin_nontemporal_store(vs, reinterpret_cast<nt4*>(g_out + row + t0));
        }
    }

    // ---------- pause compute (keys + PM from registers) + store ----------
    #pragma unroll
    for (int g = 0; g < 4; ++g) {
        const int t0 = g * 2048 + (tid << 2);
        const unsigned kk0 = kp[2 * g], kk1 = kp[2 * g + 1];
        const unsigned kk[4] = { kk0 & 0xFFFFu, kk0 >> 16, kk1 & 0xFFFFu, kk1 >> 16 };
        nt4 vp;
        #pragma unroll
        for (int c = 0; c < 4; ++c) {
            const int i = (g << 2) + c;
            const float pm = PM[i];                  // tail: m ; prefix: pp*m^2
            const float s = (float)kk[c] * INV_KSCALE;
            const float gate = 1.0f / (1.0f + __expf(-(s - thr) * INV_TEMP));
            const float tailv = scale_p * pm * pm * pm * (s * gate * pm + inv_ts6);
            vp[c] = (t0 + c < f) ? pm : tailv;
        }
        __builtin_nontemporal_store(vp, reinterpret_cast<nt4*>(g_out + out_off + row + t0));
    }
}

extern "C" void kernel_launch(void* const* d_in, const int* in_sizes, int n_in,
                              void* d_out, int out_size, void* d_ws, size_t ws_size,
                              hipStream_t stream) {
    const float* anchor = (const float*)d_in[0];
    const float* lr     = (const float*)d_in[1];
    const float* pw     = (const float*)d_in[2];
    const float* bl     = (const float*)d_in[3];
    const float* mask   = (const float*)d_in[4];
    const float* sbud   = (const float*)d_in[5];
    const float* pbud   = (const float*)d_in[6];
    const float* psp    = (const float*)d_in[7];
    const float* ppa    = (const float*)d_in[8];
    const int*   front  = (const int*)d_in[9];
    float* out = (float*)d_out;
    const int B = in_sizes[5];   // speech_budget_win has B elements
    srp_kernel<<<B, NTH, 0, stream>>>(anchor, lr, pw, bl, mask, sbud, pbud,
                                      psp, ppa, front, out, B);
}